// Round 2
// baseline (891.408 us; speedup 1.0000x reference)
//
#include <hip/hip_runtime.h>
#include <cstdint>
#include <cstddef>

#define B_ 8
#define C_ 512
#define T_ 8192

typedef unsigned short ushort_t;
typedef __attribute__((ext_vector_type(8))) short short8;            // 8 bf16 = 4 VGPR (MFMA A/B frag)
typedef __attribute__((ext_vector_type(8))) unsigned short ushort8_t;
typedef __attribute__((ext_vector_type(4))) float floatx4;           // MFMA C/D frag
typedef __attribute__((ext_vector_type(4))) unsigned int uintx4;

__device__ __forceinline__ ushort_t f2bf(float f) {
    // round-to-nearest-even fp32 -> bf16 (finite inputs)
    unsigned int u = __float_as_uint(f);
    u += 0x7FFFu + ((u >> 16) & 1u);
    return (ushort_t)(u >> 16);
}

// ---------------------------------------------------------------------------
// Fused Activation1d producing TRANSPOSED bf16 output z_T[b][t][c].
// (unchanged from v2 — verified)
// ---------------------------------------------------------------------------
#define CT   32     // channels per block
#define TT   128    // t per block
#define XSTR 148    // LDS x row stride (floats)
#define ZSTR 40     // z stage row stride (halves)

__global__ __launch_bounds__(256) void act_t_kernel(
    const float* __restrict__ X,   // [B][C][T] fp32
    const float* __restrict__ la, const float* __restrict__ lb,
    const float* __restrict__ fu, const float* __restrict__ fd,
    ushort_t* __restrict__ Zt)     // [B][T][C] bf16
{
    __shared__ __align__(16) float    xl[CT * XSTR];   // 18944 B
    __shared__ __align__(16) ushort_t zs[TT * ZSTR];   // 10240 B

    const int t0  = blockIdx.x * TT;
    const int c0  = blockIdx.y * CT;
    const int b   = blockIdx.z;
    const int tid = threadIdx.x;

    const bool interior = (t0 >= 8) && (t0 + 136 <= T_);

    // ---- stage x rows [c0..c0+31] x global t in [t0-8, t0+136) ----
    {
        const int row = tid >> 3;          // 0..31
        const int js  = tid & 7;           // 8 threads per row
        const float* Xr = X + ((size_t)b * C_ + c0 + row) * T_;
        if (interior) {
            const float* src = Xr + (t0 - 8);   // 16B-aligned (t0 % 128 == 0)
#pragma unroll
            for (int k = 0; k < 5; ++k) {
                const int seg = js + k * 8;
                if (seg < 36)
                    *(floatx4*)&xl[row * XSTR + seg * 4] = *(const floatx4*)&src[seg * 4];
            }
        } else {
#pragma unroll
            for (int e = 0; e < 18; ++e) {
                const int i = js * 18 + e;
                int t = t0 - 8 + i;
                t = min(max(t, 0), T_ - 1);
                xl[row * XSTR + i] = Xr[t];
            }
        }
    }

    float f[12], g[12];
#pragma unroll
    for (int j = 0; j < 12; ++j) { f[j] = fu[j]; g[j] = fd[j]; }

    const int cl   = tid & 31;
    const int st   = tid >> 5;       // 0..7
    const int st16 = st * 16;
    const int c    = c0 + cl;
    const float alpha = __expf(la[c]);
    const float invb  = 1.0f / (__expf(lb[c]) + 1e-9f);

    __syncthreads();

    float zacc[16];
#pragma unroll
    for (int i = 0; i < 16; ++i) zacc[i] = 0.f;

    if (interior) {
        float xw[32];
#pragma unroll
        for (int i = 0; i < 8; ++i)
            *(floatx4*)&xw[i * 4] = *(const floatx4*)&xl[cl * XSTR + st16 + i * 4];

#pragma unroll
        for (int m = 0; m < 42; ++m) {
            const int h = m >> 1;
            float y = 0.f;
            if (m & 1) {
#pragma unroll
                for (int q = 0; q < 6; ++q) y += xw[3 + h + q] * f[11 - 2 * q];
            } else {
#pragma unroll
                for (int q = 0; q < 6; ++q) y += xw[3 + h + q] * f[10 - 2 * q];
            }
            y *= 2.f;
            const float sn = __sinf(y * alpha);
            y += invb * sn * sn;
            const int dlo = (m >= 11) ? ((m - 10) >> 1) : 0;
            const int dhi = (h < 15) ? h : 15;
#pragma unroll
            for (int dt = dlo; dt <= dhi; ++dt)
                zacc[dt] += g[m - 2 * dt] * y;
        }
    } else {
        const int ts = t0 + st16;
        const float* xr = &xl[cl * XSTR];
#pragma unroll
        for (int m = 0; m < 42; ++m) {
            const int h = m >> 1;
            int n = 2 * ts - 5 + m;
            n = min(max(n, 0), 2 * T_ - 1);
            const int u    = n >> 1;
            const int base = u - (t0 - 8);
            float y = 0.f;
            if (n & 1) {
#pragma unroll
                for (int q = 0; q < 6; ++q) y += xr[base - 2 + q] * f[10 - 2 * q];
            } else {
#pragma unroll
                for (int q = 0; q < 6; ++q) y += xr[base - 3 + q] * f[11 - 2 * q];
            }
            y *= 2.f;
            const float sn = __sinf(y * alpha);
            y += invb * sn * sn;
            const int dlo = (m >= 11) ? ((m - 10) >> 1) : 0;
            const int dhi = (h < 15) ? h : 15;
#pragma unroll
            for (int dt = dlo; dt <= dhi; ++dt)
                zacc[dt] += g[m - 2 * dt] * y;
        }
    }

#pragma unroll
    for (int r = 0; r < 16; ++r)
        zs[(st16 + r) * ZSTR + cl] = f2bf(zacc[r]);

    __syncthreads();

    const int seg = tid & 3;
    const int rr  = tid >> 2;     // 0..63
#pragma unroll
    for (int p = 0; p < 2; ++p) {
        const int row = p * 64 + rr;
        *(uintx4*)&Zt[((size_t)b * T_ + t0 + row) * C_ + c0 + seg * 8] =
            *(const uintx4*)&zs[row * ZSTR + seg * 8];
    }
}

// ---------------------------------------------------------------------------
// Pack W [o][c][k] fp32 -> MFMA-fragment-ordered bf16 (unchanged):
// Wb[(k*16+cc)*32 + ot][lane][j] = W[ot*16+(lane&15)][cc*32+(lane>>4)*8+j][k]
// ---------------------------------------------------------------------------
__global__ __launch_bounds__(256) void pack_w_kernel(
    const float* __restrict__ W, ushort_t* __restrict__ Wb)
{
    const int gid   = blockIdx.x * 256 + threadIdx.x;   // 0..98303
    const int lane  = gid & 63;
    const int rest  = gid >> 6;          // k*512 + chunk*32 + ot
    const int ot    = rest & 31;
    const int chunk = (rest >> 5) & 15;
    const int k     = rest >> 9;
    const int o     = ot * 16 + (lane & 15);
    const int c0    = chunk * 32 + (lane >> 4) * 8;
    ushort8_t v;
#pragma unroll
    for (int j = 0; j < 8; ++j)
        v[j] = f2bf(W[((size_t)o * C_ + c0 + j) * 3 + k]);
    *(ushort8_t*)&Wb[(size_t)gid * 8] = v;
}

// ---------------------------------------------------------------------------
// Conv1d C->C K=3 zero-pad as 3 shifted bf16 MFMA GEMMs, fp32 accumulate.
// v3: A-fragments stream global->VGPR (Wb is L2-resident, frag-ordered) —
//     no LDS traffic for A at all.  LDS holds only B (Zt tile), double-
//     buffered, staged with global_load_lds (linear dest) + XOR-preswizzled
//     global source so the stride-128B ds_read_b128 is conflict-free.
//     One barrier per c64-chunk; A/B register fragments double-buffered so
//     each 16-MFMA burst consumes operands loaded one step earlier.
// Block tile 128(o) x 128(t); 4 waves each 64x64 via 16x16x32_bf16.
// ---------------------------------------------------------------------------
#define BROW 64            // halves per B row (c64 chunk)
#define BBUF 8320          // halves per B buffer (130 rows * 64)

__global__ __launch_bounds__(256, 3) void conv_mfma_kernel(
    const ushort_t* __restrict__ Zt,   // [B][T][C] bf16
    const ushort_t* __restrict__ Wb,   // frag-packed weights
    const float* __restrict__ bias,
    const float* __restrict__ resid,
    float* __restrict__ Out,           // [B][C][T] fp32
    const int addResid)
{
    __shared__ __align__(16) ushort_t Bl[2 * BBUF];   // 33,280 B

    const int t0  = blockIdx.x * 128;
    const int o0  = blockIdx.y * 128;
    const int b   = blockIdx.z;
    const int tid = threadIdx.x;
    const int lane = tid & 63;
    const int w    = tid >> 6;
    const int wo   = w & 1;        // o half
    const int wt   = w >> 1;       // t half

    const ushort_t* zb = Zt + (size_t)b * T_ * C_;

    floatx4 acc[4][4];
#pragma unroll
    for (int i = 0; i < 4; ++i)
#pragma unroll
        for (int j = 0; j < 4; ++j)
            acc[i][j] = (floatx4){0.f, 0.f, 0.f, 0.f};

    // ---- edge-row (t halo) constants: rows 0 and 129 handled by 16 threads
    const bool ew    = (tid < 16);
    const int  rr_e  = (tid & 8) ? 129 : 0;
    const int  seg_e = tid & 7;
    const int  t_e   = t0 - 1 + rr_e;            // t0-1 or t0+128
    const bool evld  = ew && (t_e >= 0) && (t_e < T_);
    const int  ge    = (seg_e ^ (rr_e & 7)) * 8; // pre-swizzled source seg

    // A frags: global->reg, L2-resident frag-packed weights
    auto loadA = [&](short8 af[4], int cc, int k) {
        const ushort_t* base =
            Wb + (size_t)((k * 16 + cc) * 32 + (o0 >> 4) + wo * 4) * 512 + lane * 8;
#pragma unroll
        for (int i = 0; i < 4; ++i)
            af[i] = *(const short8*)(base + i * 512);
    };

    // B frags from LDS; physical col seg = logical cq XOR (row&7)
    auto loadB = [&](short8 bf[4], const ushort_t* buf, int k, int cs) {
        const int cq = cs * 4 + (lane >> 4);
#pragma unroll
        for (int j = 0; j < 4; ++j) {
            const int rr = wt * 64 + j * 16 + (lane & 15) + k;
            bf[j] = *(const short8*)&buf[rr * BROW + ((cq ^ (rr & 7)) * 8)];
        }
    };

    // B main rows 1..128 (t = t0..t0+127, always in-bounds): 4 gll per wave,
    // linear LDS dest; global source seg pre-swizzled by (row&7).
    auto stageMain = [&](ushort_t* buf, int cc0) {
#pragma unroll
        for (int s4 = 0; s4 < 4; ++s4) {
            const int row0 = w * 32 + s4 * 8 + 1;       // wave-uniform
            const int rr   = row0 + (lane >> 3);
            const int g    = (lane & 7) ^ (rr & 7);
            const ushort_t* src = zb + (size_t)(t0 + rr - 1) * C_ + cc0 + g * 8;
            __builtin_amdgcn_global_load_lds(
                (const __attribute__((address_space(1))) unsigned int*)src,
                (__attribute__((address_space(3))) unsigned int*)(buf + row0 * BROW),
                16, 0, 0);
        }
    };

    auto mm16 = [&](short8 af[4], short8 bf[4]) {
#pragma unroll
        for (int i = 0; i < 4; ++i)
#pragma unroll
            for (int j = 0; j < 4; ++j)
                acc[i][j] = __builtin_amdgcn_mfma_f32_16x16x32_bf16(
                    af[i], bf[j], acc[i][j], 0, 0, 0);
    };

    // ---- prologue: stage chunk 0
    stageMain(Bl, 0);
    {
        uintx4 ev = (uintx4){0u, 0u, 0u, 0u};
        if (evld) ev = *(const uintx4*)&zb[(size_t)t_e * C_ + ge];
        if (ew) *(uintx4*)&Bl[rr_e * BROW + seg_e * 8] = ev;
    }
    __syncthreads();

    short8 af0[4], af1[4], bf0[4], bf1[4];

    for (int ch = 0; ch < 8; ++ch) {
        ushort_t* cur = Bl + (ch & 1) * BBUF;
        ushort_t* nxt = Bl + ((ch + 1) & 1) * BBUF;
        const int cc0 = ch * 64;    // c offset (elements)
        const int cc2 = ch * 2;     // c32-chunk index base

        loadA(af0, cc2, 0);         // step 0: k=0, cs=0
        loadB(bf0, cur, 0, 0);

        uintx4 ev = (uintx4){0u, 0u, 0u, 0u};

#pragma unroll
        for (int s = 0; s < 6; ++s) {
            const int k1  = (s + 1) >> 1;
            const int cs1 = (s + 1) & 1;
            // prefetch next step's operands BEFORE issuing the stage glls so
            // their vmcnt waits never force the gll queue to drain
            if (s & 1) {
                if (s < 5) { loadA(af0, cc2 + cs1, k1); loadB(bf0, cur, k1, cs1); }
            } else {
                if (s < 5) { loadA(af1, cc2 + cs1, k1); loadB(bf1, cur, k1, cs1); }
            }
            if (s == 2 && ch < 7) {
                stageMain(nxt, cc0 + 64);
                if (evld) ev = *(const uintx4*)&zb[(size_t)t_e * C_ + cc0 + 64 + ge];
            }
            if (s & 1) mm16(af1, bf1);
            else       mm16(af0, bf0);
        }
        if (ch < 7 && ew) *(uintx4*)&nxt[rr_e * BROW + seg_e * 8] = ev;
        __syncthreads();
    }

    // --- epilogue: D[row=o][col=t], row=(lane>>4)*4+reg, col=lane&15
    const int tc0 = t0 + wt * 64 + (lane & 15);
#pragma unroll
    for (int i = 0; i < 4; ++i) {
        const int ob = o0 + wo * 64 + i * 16 + (lane >> 4) * 4;
#pragma unroll
        for (int r = 0; r < 4; ++r) {
            const int o = ob + r;
            const float bs = bias[o];
            const size_t rowoff = ((size_t)b * C_ + o) * T_;
#pragma unroll
            for (int j = 0; j < 4; ++j) {
                const int t = tc0 + j * 16;
                float v = acc[i][j][r] + bs;
                if (addResid) v += resid[rowoff + t];
                Out[rowoff + t] = v;
            }
        }
    }
}

extern "C" void kernel_launch(void* const* d_in, const int* in_sizes, int n_in,
                              void* d_out, int out_size, void* d_ws, size_t ws_size,
                              hipStream_t stream)
{
    const float* x   = (const float*)d_in[0];
    const float* a1a = (const float*)d_in[1];
    const float* a1b = (const float*)d_in[2];
    const float* a2a = (const float*)d_in[3];
    const float* a2b = (const float*)d_in[4];
    const float* c1w = (const float*)d_in[5];
    const float* c1b = (const float*)d_in[6];
    const float* c2w = (const float*)d_in[7];
    const float* c2b = (const float*)d_in[8];
    const float* fu  = (const float*)d_in[9];
    const float* fd  = (const float*)d_in[10];
    float* out = (float*)d_out;

    // workspace layout
    ushort_t* Zt  = (ushort_t*)d_ws;                                   // 67,108,864 B
    float*    y1  = (float*)((char*)d_ws + 67108864);                  // 134,217,728 B
    ushort_t* Wb1 = (ushort_t*)((char*)d_ws + 67108864 + 134217728);   // 1,572,864 B
    ushort_t* Wb2 = Wb1 + 786432;                                      // 1,572,864 B

    dim3 agrid(T_ / TT, C_ / CT, B_);
    dim3 cgrid(T_ / 128, C_ / 128, B_);

    pack_w_kernel<<<384, 256, 0, stream>>>(c1w, Wb1);
    pack_w_kernel<<<384, 256, 0, stream>>>(c2w, Wb2);

    // xt = act1(x) -> z_T bf16
    act_t_kernel<<<agrid, 256, 0, stream>>>(x, a1a, a1b, fu, fd, Zt);
    // xt = conv1(xt) -> y1 fp32
    conv_mfma_kernel<<<cgrid, 256, 0, stream>>>(Zt, Wb1, c1b, x, y1, 0);
    // xt = act2(xt) -> z_T bf16
    act_t_kernel<<<agrid, 256, 0, stream>>>(y1, a2a, a2b, fu, fd, Zt);
    // out = conv2(xt) + x
    conv_mfma_kernel<<<cgrid, 256, 0, stream>>>(Zt, Wb2, c2b, x, out, 1);
}

// Round 4
// 730.566 us; speedup vs baseline: 1.2202x; 1.2202x over previous
//
// v4 resubmission (round-3): round-2 bench died at container level twice with no
// kernel error; full OOB/race/barrier audit found no fault mechanism. Unchanged.
#include <hip/hip_runtime.h>
#include <cstdint>
#include <cstddef>

#define B_ 8
#define C_ 512
#define T_ 8192

typedef unsigned short ushort_t;
typedef __attribute__((ext_vector_type(8))) short short8;            // 8 bf16 = 4 VGPR (MFMA A/B frag)
typedef __attribute__((ext_vector_type(8))) unsigned short ushort8_t;
typedef __attribute__((ext_vector_type(4))) float floatx4;           // MFMA C/D frag
typedef __attribute__((ext_vector_type(4))) unsigned int uintx4;

__device__ __forceinline__ ushort_t f2bf(float f) {
    // round-to-nearest-even fp32 -> bf16 (finite inputs)
    unsigned int u = __float_as_uint(f);
    u += 0x7FFFu + ((u >> 16) & 1u);
    return (ushort_t)(u >> 16);
}

// ---------------------------------------------------------------------------
// Fused Activation1d producing TRANSPOSED bf16 output z_T[b][t][c].
// (unchanged — verified)
// ---------------------------------------------------------------------------
#define CT   32     // channels per block
#define TT   128    // t per block
#define XSTR 148    // LDS x row stride (floats)
#define ZSTR 40     // z stage row stride (halves)

__global__ __launch_bounds__(256) void act_t_kernel(
    const float* __restrict__ X,   // [B][C][T] fp32
    const float* __restrict__ la, const float* __restrict__ lb,
    const float* __restrict__ fu, const float* __restrict__ fd,
    ushort_t* __restrict__ Zt)     // [B][T][C] bf16
{
    __shared__ __align__(16) float    xl[CT * XSTR];   // 18944 B
    __shared__ __align__(16) ushort_t zs[TT * ZSTR];   // 10240 B

    const int t0  = blockIdx.x * TT;
    const int c0  = blockIdx.y * CT;
    const int b   = blockIdx.z;
    const int tid = threadIdx.x;

    const bool interior = (t0 >= 8) && (t0 + 136 <= T_);

    // ---- stage x rows [c0..c0+31] x global t in [t0-8, t0+136) ----
    {
        const int row = tid >> 3;          // 0..31
        const int js  = tid & 7;           // 8 threads per row
        const float* Xr = X + ((size_t)b * C_ + c0 + row) * T_;
        if (interior) {
            const float* src = Xr + (t0 - 8);   // 16B-aligned (t0 % 128 == 0)
#pragma unroll
            for (int k = 0; k < 5; ++k) {
                const int seg = js + k * 8;
                if (seg < 36)
                    *(floatx4*)&xl[row * XSTR + seg * 4] = *(const floatx4*)&src[seg * 4];
            }
        } else {
#pragma unroll
            for (int e = 0; e < 18; ++e) {
                const int i = js * 18 + e;
                int t = t0 - 8 + i;
                t = min(max(t, 0), T_ - 1);
                xl[row * XSTR + i] = Xr[t];
            }
        }
    }

    float f[12], g[12];
#pragma unroll
    for (int j = 0; j < 12; ++j) { f[j] = fu[j]; g[j] = fd[j]; }

    const int cl   = tid & 31;
    const int st   = tid >> 5;       // 0..7
    const int st16 = st * 16;
    const int c    = c0 + cl;
    const float alpha = __expf(la[c]);
    const float invb  = 1.0f / (__expf(lb[c]) + 1e-9f);

    __syncthreads();

    float zacc[16];
#pragma unroll
    for (int i = 0; i < 16; ++i) zacc[i] = 0.f;

    if (interior) {
        float xw[32];
#pragma unroll
        for (int i = 0; i < 8; ++i)
            *(floatx4*)&xw[i * 4] = *(const floatx4*)&xl[cl * XSTR + st16 + i * 4];

#pragma unroll
        for (int m = 0; m < 42; ++m) {
            const int h = m >> 1;
            float y = 0.f;
            if (m & 1) {
#pragma unroll
                for (int q = 0; q < 6; ++q) y += xw[3 + h + q] * f[11 - 2 * q];
            } else {
#pragma unroll
                for (int q = 0; q < 6; ++q) y += xw[3 + h + q] * f[10 - 2 * q];
            }
            y *= 2.f;
            const float sn = __sinf(y * alpha);
            y += invb * sn * sn;
            const int dlo = (m >= 11) ? ((m - 10) >> 1) : 0;
            const int dhi = (h < 15) ? h : 15;
#pragma unroll
            for (int dt = dlo; dt <= dhi; ++dt)
                zacc[dt] += g[m - 2 * dt] * y;
        }
    } else {
        const int ts = t0 + st16;
        const float* xr = &xl[cl * XSTR];
#pragma unroll
        for (int m = 0; m < 42; ++m) {
            const int h = m >> 1;
            int n = 2 * ts - 5 + m;
            n = min(max(n, 0), 2 * T_ - 1);
            const int u    = n >> 1;
            const int base = u - (t0 - 8);
            float y = 0.f;
            if (n & 1) {
#pragma unroll
                for (int q = 0; q < 6; ++q) y += xr[base - 2 + q] * f[10 - 2 * q];
            } else {
#pragma unroll
                for (int q = 0; q < 6; ++q) y += xr[base - 3 + q] * f[11 - 2 * q];
            }
            y *= 2.f;
            const float sn = __sinf(y * alpha);
            y += invb * sn * sn;
            const int dlo = (m >= 11) ? ((m - 10) >> 1) : 0;
            const int dhi = (h < 15) ? h : 15;
#pragma unroll
            for (int dt = dlo; dt <= dhi; ++dt)
                zacc[dt] += g[m - 2 * dt] * y;
        }
    }

#pragma unroll
    for (int r = 0; r < 16; ++r)
        zs[(st16 + r) * ZSTR + cl] = f2bf(zacc[r]);

    __syncthreads();

    const int seg = tid & 3;
    const int rr  = tid >> 2;     // 0..63
#pragma unroll
    for (int p = 0; p < 2; ++p) {
        const int row = p * 64 + rr;
        *(uintx4*)&Zt[((size_t)b * T_ + t0 + row) * C_ + c0 + seg * 8] =
            *(const uintx4*)&zs[row * ZSTR + seg * 8];
    }
}

// ---------------------------------------------------------------------------
// Pack W [o][c][k] fp32 -> MFMA-fragment-ordered bf16 (unchanged):
// Wb[(k*16+cc)*32 + ot][lane][j] = W[ot*16+(lane&15)][cc*32+(lane>>4)*8+j][k]
// ---------------------------------------------------------------------------
__global__ __launch_bounds__(256) void pack_w_kernel(
    const float* __restrict__ W, ushort_t* __restrict__ Wb)
{
    const int gid   = blockIdx.x * 256 + threadIdx.x;   // 0..98303
    const int lane  = gid & 63;
    const int rest  = gid >> 6;          // k*512 + chunk*32 + ot
    const int ot    = rest & 31;
    const int chunk = (rest >> 5) & 15;
    const int k     = rest >> 9;
    const int o     = ot * 16 + (lane & 15);
    const int c0    = chunk * 32 + (lane >> 4) * 8;
    ushort8_t v;
#pragma unroll
    for (int j = 0; j < 8; ++j)
        v[j] = f2bf(W[((size_t)o * C_ + c0 + j) * 3 + k]);
    *(ushort8_t*)&Wb[(size_t)gid * 8] = v;
}

// ---------------------------------------------------------------------------
// Conv1d C->C K=3 zero-pad as 3 shifted bf16 MFMA GEMMs, fp32 accumulate.
// v4: A via global_load_lds into LDS (v2 path, conflict-free stream reads),
//     B in paired-row swizzled LDS (two 64B t-rows per 128B LDS row,
//     slot = (e*4+q) ^ (pr&7); <=2-way = free), staged with linear gll dest
//     + inverse-swizzled per-lane GLOBAL source (both-sides-or-neither).
//     Both double-buffered at c32 granularity; ONE barrier per chunk; stage
//     for chunk c+1 issued before chunk c's 48 MFMA, so the pre-barrier
//     vmcnt(0) drain is covered by compute (m97 structure).
// Block tile 128(o) x 128(t); 4 waves each 64x64 via 16x16x32_bf16.
// LDS = 2*24KB (A) + 2*8.25KB (B) = 64.5KB -> 2 blocks/CU.
// ---------------------------------------------------------------------------
#define ABUF 12288   // halves per A buffer (24 segs * 512)
#define BBUF 4224    // halves per B buffer (66 LDS rows * 64)

__global__ __launch_bounds__(256, 2) void conv_mfma_kernel(
    const ushort_t* __restrict__ Zt,   // [B][T][C] bf16
    const ushort_t* __restrict__ Wb,   // frag-packed weights
    const float* __restrict__ bias,
    const float* __restrict__ resid,
    float* __restrict__ Out,           // [B][C][T] fp32
    const int addResid)
{
    __shared__ __align__(16) ushort_t Al[2 * ABUF];   // 49,152 B
    __shared__ __align__(16) ushort_t Bs[2 * BBUF];   // 16,896 B

    const int t0  = blockIdx.x * 128;
    const int o0  = blockIdx.y * 128;
    const int b   = blockIdx.z;
    const int tid = threadIdx.x;
    const int lane = tid & 63;
    const int w    = tid >> 6;
    const int wo   = w & 1;        // o half
    const int wt   = w >> 1;       // t half

    const ushort_t* zb = Zt + (size_t)b * T_ * C_;

    floatx4 acc[4][4];
#pragma unroll
    for (int i = 0; i < 4; ++i)
#pragma unroll
        for (int j = 0; j < 4; ++j)
            acc[i][j] = (floatx4){0.f, 0.f, 0.f, 0.f};

    // ---- B read offsets (halves), chunk-invariant.
    // t-row rr (t = t0-1+rr) lives at LDS row pr=(rr+1)>>1, sub-row e=(rr+1)&1;
    // 16B seg q at slot ((e<<2)|q) ^ (pr&7).
    int bofs[3][4];
#pragma unroll
    for (int k = 0; k < 3; ++k)
#pragma unroll
        for (int j = 0; j < 4; ++j) {
            const int rr = wt * 64 + j * 16 + (lane & 15) + k;
            const int pr = (rr + 1) >> 1;
            const int slot = ((((rr + 1) & 1) << 2) | (lane >> 4)) ^ (pr & 7);
            bofs[k][j] = pr * 64 + slot * 8;
        }

    const int aoff = wo * 2048 + lane * 8;   // A read base (halves)

    // ---- B main-stage source precompute (inverse swizzle), G-invariant parts.
    // gll G covers t-rows rr = 1+16G..16+16G -> LDS rows pr = 1+8G..8+8G.
    // lane -> (pr = 1+8G+(lane>>3), slot s = lane&7); u = s ^ (pr&7) (G-inv);
    // e = u>>2, q = u&3, rr = 2*pr-1+e -> t = t0 + 2*(1+(lane>>3)) - 2 + e + 16G.
    const int prw = 1 + (lane >> 3);
    const int ub  = (lane & 7) ^ (prw & 7);
    const int tb0 = t0 + 2 * prw - 2 + (ub >> 2);   // + 16*G
    const int cb0 = (ub & 3) * 8;                   // + chunk*32

    // ---- edge t-rows (rr=0: t0-1, rr=129: t0+128) via reg path, 8 threads
    const bool eth = (tid < 8);
    const int  eq  = tid & 3;
    const int  ehi = (tid >> 2) & 1;
    const int  t_e = ehi ? (t0 + 128) : (t0 - 1);
    const bool evv = eth && (t_e >= 0) && (t_e < T_);
    const int  edst = ehi ? (65 * 64 + (eq ^ 1) * 8)   // rr=129: pr=65,e=0
                          : ((4 + eq) * 8);            // rr=0:   pr=0, e=1
    const ushort_t* esrc0 = zb + (size_t)t_e * C_ + eq * 8;   // + chunk*32

    auto stageA = [&](ushort_t* abuf, int ch) {
#pragma unroll
        for (int s = 0; s < 6; ++s) {
            const int seg = w * 6 + s;
            const int k   = seg >> 3;
            const int ot8 = seg & 7;
            const ushort_t* src =
                Wb + (size_t)(((k * 16 + ch) * 32) + (o0 >> 4) + ot8) * 512 + lane * 8;
            __builtin_amdgcn_global_load_lds(
                (const __attribute__((address_space(1))) unsigned int*)src,
                (__attribute__((address_space(3))) unsigned int*)(abuf + seg * 512),
                16, 0, 0);
        }
    };
    auto stageB = [&](ushort_t* bbuf, int ch) {
#pragma unroll
        for (int gi = 0; gi < 2; ++gi) {
            const int G = w * 2 + gi;
            const ushort_t* src = zb + (size_t)(tb0 + 16 * G) * C_ + ch * 32 + cb0;
            __builtin_amdgcn_global_load_lds(
                (const __attribute__((address_space(1))) unsigned int*)src,
                (__attribute__((address_space(3))) unsigned int*)(bbuf + (1 + 8 * G) * 64),
                16, 0, 0);
        }
    };

    // ---- prologue: stage chunk 0
    stageA(Al, 0);
    stageB(Bs, 0);
    {
        uintx4 ev = (uintx4){0u, 0u, 0u, 0u};
        if (evv) ev = *(const uintx4*)esrc0;
        if (eth) *(uintx4*)&Bs[edst] = ev;
    }
    __syncthreads();

#pragma unroll 2
    for (int ch = 0; ch < 16; ++ch) {
        ushort_t* curA = Al + (ch & 1) * ABUF;
        ushort_t* curB = Bs + (ch & 1) * BBUF;
        ushort_t* nxtA = Al + ((ch + 1) & 1) * ABUF;
        ushort_t* nxtB = Bs + ((ch + 1) & 1) * BBUF;

        uintx4 ev = (uintx4){0u, 0u, 0u, 0u};
        if (ch < 15) {
            stageA(nxtA, ch + 1);
            stageB(nxtB, ch + 1);
            if (evv) ev = *(const uintx4*)(esrc0 + (ch + 1) * 32);
        }

#pragma unroll
        for (int k = 0; k < 3; ++k) {
            short8 af[4], bf[4];
#pragma unroll
            for (int i = 0; i < 4; ++i)
                af[i] = *(const short8*)&curA[aoff + (k * 8 + i) * 512];
#pragma unroll
            for (int j = 0; j < 4; ++j)
                bf[j] = *(const short8*)&curB[bofs[k][j]];
#pragma unroll
            for (int i = 0; i < 4; ++i)
#pragma unroll
                for (int j = 0; j < 4; ++j)
                    acc[i][j] = __builtin_amdgcn_mfma_f32_16x16x32_bf16(
                        af[i], bf[j], acc[i][j], 0, 0, 0);
        }

        if (ch < 15) {
            if (eth) *(uintx4*)&nxtB[edst] = ev;
            __syncthreads();
        }
    }

    // --- epilogue: D[row=o][col=t], row=(lane>>4)*4+reg, col=lane&15
    const int tc0 = t0 + wt * 64 + (lane & 15);
#pragma unroll
    for (int i = 0; i < 4; ++i) {
        const int ob = o0 + wo * 64 + i * 16 + (lane >> 4) * 4;
#pragma unroll
        for (int r = 0; r < 4; ++r) {
            const int o = ob + r;
            const float bs = bias[o];
            const size_t rowoff = ((size_t)b * C_ + o) * T_;
#pragma unroll
            for (int j = 0; j < 4; ++j) {
                const int t = tc0 + j * 16;
                float v = acc[i][j][r] + bs;
                if (addResid) v += resid[rowoff + t];
                Out[rowoff + t] = v;
            }
        }
    }
}

extern "C" void kernel_launch(void* const* d_in, const int* in_sizes, int n_in,
                              void* d_out, int out_size, void* d_ws, size_t ws_size,
                              hipStream_t stream)
{
    const float* x   = (const float*)d_in[0];
    const float* a1a = (const float*)d_in[1];
    const float* a1b = (const float*)d_in[2];
    const float* a2a = (const float*)d_in[3];
    const float* a2b = (const float*)d_in[4];
    const float* c1w = (const float*)d_in[5];
    const float* c1b = (const float*)d_in[6];
    const float* c2w = (const float*)d_in[7];
    const float* c2b = (const float*)d_in[8];
    const float* fu  = (const float*)d_in[9];
    const float* fd  = (const float*)d_in[10];
    float* out = (float*)d_out;

    // workspace layout
    ushort_t* Zt  = (ushort_t*)d_ws;                                   // 67,108,864 B
    float*    y1  = (float*)((char*)d_ws + 67108864);                  // 134,217,728 B
    ushort_t* Wb1 = (ushort_t*)((char*)d_ws + 67108864 + 134217728);   // 1,572,864 B
    ushort_t* Wb2 = Wb1 + 786432;                                      // 1,572,864 B

    dim3 agrid(T_ / TT, C_ / CT, B_);
    dim3 cgrid(T_ / 128, C_ / 128, B_);

    pack_w_kernel<<<384, 256, 0, stream>>>(c1w, Wb1);
    pack_w_kernel<<<384, 256, 0, stream>>>(c2w, Wb2);

    // xt = act1(x) -> z_T bf16
    act_t_kernel<<<agrid, 256, 0, stream>>>(x, a1a, a1b, fu, fd, Zt);
    // xt = conv1(xt) -> y1 fp32
    conv_mfma_kernel<<<cgrid, 256, 0, stream>>>(Zt, Wb1, c1b, x, y1, 0);
    // xt = act2(xt) -> z_T bf16
    act_t_kernel<<<agrid, 256, 0, stream>>>(y1, a2a, a2b, fu, fd, Zt);
    // out = conv2(xt) + x
    conv_mfma_kernel<<<cgrid, 256, 0, stream>>>(Zt, Wb2, c2b, x, out, 1);
}